// Round 4
// baseline (915.957 us; speedup 1.0000x reference)
//
#include <hip/hip_runtime.h>
#include <math.h>

#define BB 512
#define NN 128
#define DD 256
#define HH 8
#define NC 5
#define BH 64
#define SCALE_INV 0.17677669529663687f  // 1/sqrt(32)

__device__ __forceinline__ void breduce2(float &a, float &b, float* red){
  #pragma unroll
  for (int m=32;m>=1;m>>=1){ a += __shfl_xor(a,m); b += __shfl_xor(b,m); }
  int w = threadIdx.x>>6, l = threadIdx.x&63;
  if (l==0){ red[w*2]=a; red[w*2+1]=b; }
  __syncthreads();
  a = red[0]+red[2]+red[4]+red[6];
  b = red[1]+red[3]+red[5]+red[7];
  __syncthreads();
}

// One-shot transpose of pWq and eWq (256x256 each) so prep's U5 loop reads
// them coalesced. grid(8,8,2), block 256 (32x8 tile loops).
__global__ __launch_bounds__(256) void transpose_kernel(
  const float* __restrict__ A, const float* __restrict__ B,
  float* __restrict__ AT, float* __restrict__ BT)
{
  __shared__ float tile[32][33];
  int bx = blockIdx.x, by = blockIdx.y, z = blockIdx.z;
  const float* src = z ? B : A;
  float* dst = z ? BT : AT;
  int tx = threadIdx.x & 31, ty = threadIdx.x >> 5;
  #pragma unroll
  for (int k=0;k<4;++k)
    tile[ty+8*k][tx] = src[(size_t)(by*32+ty+8*k)*DD + bx*32+tx];
  __syncthreads();
  #pragma unroll
  for (int k=0;k<4;++k)
    dst[(size_t)(bx*32+ty+8*k)*DD + by*32+tx] = tile[tx][ty+8*k];
}

// Per-batch prep: ego LN1 -> Ve -> v2; top-5; candidate x2; K5/V5;
// folded U5/eU5 (query side, pre-scaled) and W5 (output side); bias MLP.
// All global weight reads coalesced (pWq/eWq via pre-transposed copies).
__global__ __launch_bounds__(256) void prep_kernel(
  const float* __restrict__ tokens, const int* __restrict__ ego_idx,
  const float* __restrict__ dist,
  const float* __restrict__ ln1_g, const float* __restrict__ ln1_b,
  const float* __restrict__ ln2_g, const float* __restrict__ ln2_b,
  const float* __restrict__ cWv, const float* __restrict__ cWo,
  const float* __restrict__ pWqT, const float* __restrict__ eWqT,
  const float* __restrict__ pWk, const float* __restrict__ pWv,
  const float* __restrict__ pWo,
  const float* __restrict__ bW1, const float* __restrict__ bb1,
  const float* __restrict__ bW2, const float* __restrict__ bb2,
  float* __restrict__ v2g, int* __restrict__ candI,
  float* __restrict__ U5, float* __restrict__ eU5, float* __restrict__ W5,
  float* __restrict__ biasO)
{
  __shared__ float sA[DD], sB[DD], sV2[DD];
  __shared__ float sX2[NC][DD], sK5[NC][DD], sV5[NC][DD];
  __shared__ float red[8];
  __shared__ int sCI[NC];
  __shared__ float sCD[NC];
  __shared__ float sW1[2*BH], sB1[BH], sW2[BH*HH], sB2[HH];

  int b = blockIdx.x, t = threadIdx.x;
  int ego = ego_idx[b];

  if (t < 2*BH) sW1[t] = bW1[t];
  if (t < BH)   sB1[t] = bb1[t];
  for (int i=t;i<BH*HH;i+=256) sW2[i]=bW2[i];
  if (t < HH)   sB2[t] = bb2[t];

  // ---- LN1 on ego token ----
  float xe = tokens[((size_t)b*NN+ego)*DD + t];
  float a = xe, sq = xe*xe;
  breduce2(a, sq, red);
  float mu = a*(1.0f/DD), var = sq*(1.0f/DD)-mu*mu;
  float rs = rsqrtf(var+1e-5f);
  sA[t] = (xe-mu)*rs*ln1_g[t] + ln1_b[t];
  __syncthreads();
  // ---- Ve = x1e @ cWv ----
  {
    float acc=0.f;
    for (int d=0;d<DD;++d) acc += sA[d]*cWv[d*DD+t];
    sB[t]=acc;
  }
  __syncthreads();
  // ---- v2 = Ve @ cWo ----
  {
    float acc=0.f;
    for (int d=0;d<DD;++d) acc += sB[d]*cWo[d*DD+t];
    sV2[t]=acc;
    v2g[(size_t)b*DD+t]=acc;
  }
  // ---- top-5 smallest (dist, idx) packed u64 wave-min, wave 0 ----
  if (t < 64){
    unsigned long long k0 = (((unsigned long long)__float_as_uint(dist[b*NN+t]))<<32) | (unsigned)t;
    unsigned long long k1 = (((unsigned long long)__float_as_uint(dist[b*NN+t+64]))<<32) | (unsigned)(t+64);
    for (int r=0;r<NC;++r){
      unsigned long long m = k0<k1?k0:k1;
      #pragma unroll
      for (int s=32;s>=1;s>>=1){
        unsigned long long o = __shfl_xor(m, s);
        if (o<m) m=o;
      }
      int idx = (int)(m & 0xffffffffULL);
      if (t==0){
        sCI[r]=idx;
        sCD[r]=__uint_as_float((unsigned)(m>>32));
        candI[b*8+r]=idx;
      }
      if (idx==t)    k0=~0ULL;
      if (idx==t+64) k1=~0ULL;
    }
  }
  __syncthreads();
  // ---- candidate rows: x2 = LN2(tokens[cand] + v2) ----
  for (int c=0;c<NC;++c){
    float h1 = tokens[((size_t)b*NN+sCI[c])*DD + t] + sV2[t];
    float s=h1, s2=h1*h1;
    breduce2(s,s2,red);
    float m2 = s*(1.0f/DD), v = s2*(1.0f/DD)-m2*m2;
    float r2 = rsqrtf(v+1e-5f);
    sX2[c][t] = (h1-m2)*r2*ln2_g[t]+ln2_b[t];
  }
  __syncthreads();
  // ---- K5 = x2c @ pWk ; V5 = x2c @ pWv ----
  {
    float k0=0,k1=0,k2=0,k3=0,k4=0, v0=0,v1=0,v2=0,v3=0,v4=0;
    for (int d=0;d<DD;++d){
      float wk = pWk[d*DD+t], wv = pWv[d*DD+t];
      float xa=sX2[0][d], xb=sX2[1][d], xc=sX2[2][d], xd=sX2[3][d], xe2=sX2[4][d];
      k0+=xa*wk; k1+=xb*wk; k2+=xc*wk; k3+=xd*wk; k4+=xe2*wk;
      v0+=xa*wv; v1+=xb*wv; v2+=xc*wv; v3+=xd*wv; v4+=xe2*wv;
    }
    sK5[0][t]=k0; sK5[1][t]=k1; sK5[2][t]=k2; sK5[3][t]=k3; sK5[4][t]=k4;
    sV5[0][t]=v0; sV5[1][t]=v1; sV5[2][t]=v2; sV5[3][t]=v3; sV5[4][t]=v4;
  }
  __syncthreads();
  // ---- U5[c][h][i] = SCALE_INV * sum_dd pWqT[h*32+dd][i]*K5[c][h*32+dd] ----
  for (int h=0;h<HH;++h){
    float u0=0,u1=0,u2=0,u3=0,u4=0, e0=0,e1=0,e2=0,e3=0,e4=0;
    #pragma unroll
    for (int dd=0;dd<32;++dd){
      int d = h*32+dd;
      float wq = pWqT[(size_t)d*DD+t];   // coalesced (t across lanes)
      float we = eWqT[(size_t)d*DD+t];
      float a0=sK5[0][d], a1=sK5[1][d], a2=sK5[2][d], a3=sK5[3][d], a4=sK5[4][d];
      u0+=wq*a0; u1+=wq*a1; u2+=wq*a2; u3+=wq*a3; u4+=wq*a4;
      e0+=we*a0; e1+=we*a1; e2+=we*a2; e3+=we*a3; e4+=we*a4;
    }
    size_t base = (size_t)b*NC*HH*DD + (size_t)h*DD + t;
    U5 [base + 0*HH*DD]=u0*SCALE_INV; eU5[base + 0*HH*DD]=e0*SCALE_INV;
    U5 [base + 1*HH*DD]=u1*SCALE_INV; eU5[base + 1*HH*DD]=e1*SCALE_INV;
    U5 [base + 2*HH*DD]=u2*SCALE_INV; eU5[base + 2*HH*DD]=e2*SCALE_INV;
    U5 [base + 3*HH*DD]=u3*SCALE_INV; eU5[base + 3*HH*DD]=e3*SCALE_INV;
    U5 [base + 4*HH*DD]=u4*SCALE_INV; eU5[base + 4*HH*DD]=e4*SCALE_INV;
  }
  // ---- W5[c][h][j] = sum_dd V5[c][h*32+dd] * pWo[h*32+dd, j] ----
  for (int h=0;h<HH;++h){
    float w0=0,w1=0,w2=0,w3=0,w4=0;
    #pragma unroll
    for (int dd=0;dd<32;++dd){
      int d=h*32+dd;
      float wo = pWo[d*DD+t];
      w0+=sV5[0][d]*wo; w1+=sV5[1][d]*wo; w2+=sV5[2][d]*wo;
      w3+=sV5[3][d]*wo; w4+=sV5[4][d]*wo;
    }
    size_t base = (size_t)b*NC*HH*DD + (size_t)h*DD + t;
    W5[base + 0*HH*DD]=w0; W5[base + 1*HH*DD]=w1; W5[base + 2*HH*DD]=w2;
    W5[base + 3*HH*DD]=w3; W5[base + 4*HH*DD]=w4;
  }
  // ---- bias MLP table: bias[b][n][c][h] ----
  for (int p=t;p<NN*NC;p+=256){
    int n=p/NC, c=p%NC;
    float di = dist[b*NN+n], dj = sCD[c];
    float o0=0,o1=0,o2=0,o3=0,o4=0,o5=0,o6=0,o7=0;
    for (int j=0;j<BH;++j){
      float hd = fmaxf(di*sW1[j]+dj*sW1[BH+j]+sB1[j], 0.f);
      o0+=hd*sW2[j*HH+0]; o1+=hd*sW2[j*HH+1];
      o2+=hd*sW2[j*HH+2]; o3+=hd*sW2[j*HH+3];
      o4+=hd*sW2[j*HH+4]; o5+=hd*sW2[j*HH+5];
      o6+=hd*sW2[j*HH+6]; o7+=hd*sW2[j*HH+7];
    }
    float* bp = biasO + (((size_t)b*NN+n)*NC+c)*HH;
    bp[0]=o0+sB2[0]; bp[1]=o1+sB2[1]; bp[2]=o2+sB2[2]; bp[3]=o3+sB2[3];
    bp[4]=o4+sB2[4]; bp[5]=o5+sB2[5]; bp[6]=o6+sB2[6]; bp[7]=o7+sB2[7];
  }
}

// 8 named partials (one per h) -> lane holds full sum for h=lane>>3.
__device__ __forceinline__ float reduce40(
  float q0,float q1,float q2,float q3,float q4,float q5,float q6,float q7,int lane)
{
  const bool b5 = (lane&32)!=0, b4 = (lane&16)!=0, b3 = (lane&8)!=0;
  float r0 = (b5? q4:q0) + __shfl_xor(b5? q0:q4, 32);
  float r1 = (b5? q5:q1) + __shfl_xor(b5? q1:q5, 32);
  float r2 = (b5? q6:q2) + __shfl_xor(b5? q2:q6, 32);
  float r3 = (b5? q7:q3) + __shfl_xor(b5? q3:q7, 32);
  float t0 = (b4? r2:r0) + __shfl_xor(b4? r0:r2, 16);
  float t1 = (b4? r3:r1) + __shfl_xor(b4? r1:r3, 16);
  float s  = (b3? t1:t0) + __shfl_xor(b3? t0:t1, 8);
  s += __shfl_xor(s,4); s += __shfl_xor(s,2); s += __shfl_xor(s,1);
  return s;
}

// one (c)-block score for one row: 8 float4 reads + reduce40
__device__ __forceinline__ float dotred(const float* base, float xa, float xb,
                                        float xc, float xd, int lane)
{
  const float* ub = base + 4*lane;
  float4 u;
  u=*(const float4*)(ub+0*DD); float q0=xa*u.x+xb*u.y+xc*u.z+xd*u.w;
  u=*(const float4*)(ub+1*DD); float q1=xa*u.x+xb*u.y+xc*u.z+xd*u.w;
  u=*(const float4*)(ub+2*DD); float q2=xa*u.x+xb*u.y+xc*u.z+xd*u.w;
  u=*(const float4*)(ub+3*DD); float q3=xa*u.x+xb*u.y+xc*u.z+xd*u.w;
  u=*(const float4*)(ub+4*DD); float q4=xa*u.x+xb*u.y+xc*u.z+xd*u.w;
  u=*(const float4*)(ub+5*DD); float q5=xa*u.x+xb*u.y+xc*u.z+xd*u.w;
  u=*(const float4*)(ub+6*DD); float q6=xa*u.x+xb*u.y+xc*u.z+xd*u.w;
  u=*(const float4*)(ub+7*DD); float q7=xa*u.x+xb*u.y+xc*u.z+xd*u.w;
  return reduce40(q0,q1,q2,q3,q4,q5,q6,q7,lane);
}

// One block per batch, 512 threads = 8 waves. Each wave owns 16 rows,
// processed in 4 batches of 4 rows so every U5/W5 ds_read feeds 4 rows.
// LDS: U5 + W5 = 80 KB -> 2 blocks/CU. All array indices compile-time.
__global__ __launch_bounds__(512, 4) void main_kernel(
  const float* __restrict__ tokens, const int* __restrict__ ego_idx,
  const float* __restrict__ ln2_g, const float* __restrict__ ln2_b,
  const float* __restrict__ v2g, const int* __restrict__ candI,
  const float* __restrict__ U5g, const float* __restrict__ eU5g,
  const float* __restrict__ W5g, const float* __restrict__ biasO,
  float* __restrict__ out)
{
  __shared__ float sU[NC*HH*DD];
  __shared__ float sW[NC*HH*DD];
  int b = blockIdx.x, t = threadIdx.x;
  int lane = t & 63, wave = t >> 6;
  {
    const float4* srcU = (const float4*)(U5g + (size_t)b*NC*HH*DD);
    const float4* srcW = (const float4*)(W5g + (size_t)b*NC*HH*DD);
    float4* dU = (float4*)sU; float4* dW = (float4*)sW;
    #pragma unroll
    for (int i=0;i<5;++i){ dU[t+512*i]=srcU[t+512*i]; dW[t+512*i]=srcW[t+512*i]; }
  }
  int ego = ego_idx[b];
  const int* cip = candI + b*8;
  int ci0=cip[0],ci1=cip[1],ci2=cip[2],ci3=cip[3],ci4=cip[4];
  float4 v2r = *(const float4*)(v2g + (size_t)b*DD + 4*lane);
  float4 g4  = *(const float4*)(ln2_g + 4*lane);
  float4 b4  = *(const float4*)(ln2_b + 4*lane);
  int h_lane = lane>>3;
  __syncthreads();

  for (int g=0; g<4; ++g){
    int n0 = wave + g*32;           // rows n0 + 8*r, r=0..3
    // ---- load 4 token rows, pre-LN h, LN2 -> x ----
    float hv[4][4], x[4][4];
    #pragma unroll
    for (int r=0;r<4;++r){
      float4 tk = *(const float4*)(tokens + ((size_t)b*NN + n0 + 8*r)*DD + 4*lane);
      hv[r][0]=tk.x+v2r.x; hv[r][1]=tk.y+v2r.y;
      hv[r][2]=tk.z+v2r.z; hv[r][3]=tk.w+v2r.w;
      float s1 = hv[r][0]+hv[r][1]+hv[r][2]+hv[r][3];
      float s2 = hv[r][0]*hv[r][0]+hv[r][1]*hv[r][1]+hv[r][2]*hv[r][2]+hv[r][3]*hv[r][3];
      #pragma unroll
      for (int m=32;m>=1;m>>=1){ s1+=__shfl_xor(s1,m); s2+=__shfl_xor(s2,m); }
      float mu = s1*(1.0f/DD);
      float var = s2*(1.0f/DD)-mu*mu;
      float rs = rsqrtf(var+1e-5f);
      x[r][0]=(hv[r][0]-mu)*rs*g4.x+b4.x;
      x[r][1]=(hv[r][1]-mu)*rs*g4.y+b4.y;
      x[r][2]=(hv[r][2]-mu)*rs*g4.z+b4.z;
      x[r][3]=(hv[r][3]-mu)*rs*g4.w+b4.w;
    }
    // ---- scores: share each U5 read across 4 rows ----
    float sc[NC][4];
    #pragma unroll
    for (int c=0;c<NC;++c){
      float q[8][4];
      #pragma unroll
      for (int h=0;h<HH;++h){
        const float4 u = *(const float4*)(sU + (c*HH+h)*DD + 4*lane);
        #pragma unroll
        for (int r=0;r<4;++r)
          q[h][r] = x[r][0]*u.x + x[r][1]*u.y + x[r][2]*u.z + x[r][3]*u.w;
      }
      #pragma unroll
      for (int r=0;r<4;++r)
        sc[c][r] = reduce40(q[0][r],q[1][r],q[2][r],q[3][r],
                            q[4][r],q[5][r],q[6][r],q[7][r],lane);
    }
    // ---- ego fix-up (wave-uniform; at most one row per block) ----
    #pragma unroll
    for (int r=0;r<4;++r){
      if (n0 + 8*r == ego){
        const float* eb = eU5g + (size_t)b*NC*HH*DD;
        #pragma unroll
        for (int c=0;c<NC;++c)
          sc[c][r] = dotred(eb + c*HH*DD, x[r][0],x[r][1],x[r][2],x[r][3], lane);
      }
    }
    // ---- bias + mask + softmax (per row, lane-local over 5) ----
    #pragma unroll
    for (int r=0;r<4;++r){
      int n = n0 + 8*r;
      const float* bp = biasO + ((size_t)b*NN+n)*NC*HH + h_lane;
      float bi0=bp[0], bi1=bp[8], bi2=bp[16], bi3=bp[24], bi4=bp[32];
      int pos = (ci0==n)?0:(ci1==n)?1:(ci2==n)?2:(ci3==n)?3:(ci4==n)?4:5;
      int bad = (pos==5)?4:pos;
      float s0 = (bad==0)? -1e30f : sc[0][r]+bi0;
      float s1 = (bad==1)? -1e30f : sc[1][r]+bi1;
      float s2 = (bad==2)? -1e30f : sc[2][r]+bi2;
      float s3 = (bad==3)? -1e30f : sc[3][r]+bi3;
      float s4 = (bad==4)? -1e30f : sc[4][r]+bi4;
      float mx = fmaxf(fmaxf(fmaxf(s0,s1),fmaxf(s2,s3)),s4);
      float e0=__expf(s0-mx), e1=__expf(s1-mx), e2=__expf(s2-mx);
      float e3=__expf(s3-mx), e4=__expf(s4-mx);
      float inv = 1.0f/(e0+e1+e2+e3+e4);
      sc[0][r]=e0*inv; sc[1][r]=e1*inv; sc[2][r]=e2*inv;
      sc[3][r]=e3*inv; sc[4][r]=e4*inv;
    }
    // ---- output: share each W5 read across 4 rows; w via readlane ----
    float o[4][4];
    #pragma unroll
    for (int r=0;r<4;++r){ o[r][0]=0.f; o[r][1]=0.f; o[r][2]=0.f; o[r][3]=0.f; }
    #pragma unroll
    for (int c=0;c<NC;++c){
      #pragma unroll
      for (int h=0;h<HH;++h){
        const float4 wr = *(const float4*)(sW + (c*HH+h)*DD + 4*lane);
        #pragma unroll
        for (int r=0;r<4;++r){
          float wv = __int_as_float(
              __builtin_amdgcn_readlane(__float_as_int(sc[c][r]), h*8));
          o[r][0]+=wv*wr.x; o[r][1]+=wv*wr.y; o[r][2]+=wv*wr.z; o[r][3]+=wv*wr.w;
        }
      }
    }
    #pragma unroll
    for (int r=0;r<4;++r){
      float4 res = make_float4(hv[r][0]+o[r][0], hv[r][1]+o[r][1],
                               hv[r][2]+o[r][2], hv[r][3]+o[r][3]);
      *(float4*)(out + ((size_t)b*NN + n0 + 8*r)*DD + 4*lane) = res;
    }
  }
}

extern "C" void kernel_launch(void* const* d_in, const int* in_sizes, int n_in,
                              void* d_out, int out_size, void* d_ws, size_t ws_size,
                              hipStream_t stream) {
  (void)in_sizes; (void)n_in; (void)out_size; (void)ws_size;
  const float* tokens = (const float*)d_in[0];
  const int*   ego_idx= (const int*)  d_in[1];
  const float* dist   = (const float*)d_in[2];
  // d_in[3] = ego_speed (unused by reference)
  const float* ln1_g  = (const float*)d_in[4];
  const float* ln1_b  = (const float*)d_in[5];
  const float* ln2_g  = (const float*)d_in[6];
  const float* ln2_b  = (const float*)d_in[7];
  // d_in[8]=cWq, d_in[9]=cWk dead: softmax over singleton axis == 1
  const float* cWv    = (const float*)d_in[10];
  const float* cWo    = (const float*)d_in[11];
  const float* pWq    = (const float*)d_in[12];
  const float* eWq    = (const float*)d_in[13];
  const float* pWk    = (const float*)d_in[14];
  const float* pWv    = (const float*)d_in[15];
  const float* pWo    = (const float*)d_in[16];
  const float* bW1    = (const float*)d_in[17];
  const float* bb1    = (const float*)d_in[18];
  const float* bW2    = (const float*)d_in[19];
  const float* bb2    = (const float*)d_in[20];
  float* outp = (float*)d_out;

  char* w = (char*)d_ws;
  float* v2g   = (float*)w; w += (size_t)BB*DD*4;
  int*   candI = (int*)w;   w += (size_t)BB*8*4;
  float* U5    = (float*)w; w += (size_t)BB*NC*HH*DD*4;
  float* eU5   = (float*)w; w += (size_t)BB*NC*HH*DD*4;
  float* W5    = (float*)w; w += (size_t)BB*NC*HH*DD*4;
  float* biasO = (float*)w; w += (size_t)BB*NN*NC*HH*4;
  float* pWqT  = (float*)w; w += (size_t)DD*DD*4;
  float* eWqT  = (float*)w; w += (size_t)DD*DD*4;

  transpose_kernel<<<dim3(8,8,2), dim3(256), 0, stream>>>(pWq, eWq, pWqT, eWqT);

  prep_kernel<<<dim3(BB), dim3(256), 0, stream>>>(
      tokens, ego_idx, dist, ln1_g, ln1_b, ln2_g, ln2_b,
      cWv, cWo, pWqT, eWqT, pWk, pWv, pWo, bW1, bb1, bW2, bb2,
      v2g, candI, U5, eU5, W5, biasO);

  main_kernel<<<dim3(BB), dim3(512), 0, stream>>>(
      tokens, ego_idx, ln2_g, ln2_b, v2g, candI, U5, eU5, W5, biasO, outp);
}

// Round 5
// 444.922 us; speedup vs baseline: 2.0587x; 2.0587x over previous
//
#include <hip/hip_runtime.h>
#include <math.h>

#define BB 512
#define NN 128
#define DD 256
#define HH 8
#define NC 5
#define BH 64
#define SCALE_INV 0.17677669529663687f  // 1/sqrt(32)

__device__ __forceinline__ void breduce2(float &a, float &b, float* red){
  #pragma unroll
  for (int m=32;m>=1;m>>=1){ a += __shfl_xor(a,m); b += __shfl_xor(b,m); }
  int w = threadIdx.x>>6, l = threadIdx.x&63;
  if (l==0){ red[w*2]=a; red[w*2+1]=b; }
  __syncthreads();
  a = red[0]+red[2]+red[4]+red[6];
  b = red[1]+red[3]+red[5]+red[7];
  __syncthreads();
}

// One-shot transpose of pWq and eWq (256x256 each) so prep's U5 loop reads
// them coalesced. grid(8,8,2), block 256 (32x8 tile loops).
__global__ __launch_bounds__(256) void transpose_kernel(
  const float* __restrict__ A, const float* __restrict__ B,
  float* __restrict__ AT, float* __restrict__ BT)
{
  __shared__ float tile[32][33];
  int bx = blockIdx.x, by = blockIdx.y, z = blockIdx.z;
  const float* src = z ? B : A;
  float* dst = z ? BT : AT;
  int tx = threadIdx.x & 31, ty = threadIdx.x >> 5;
  #pragma unroll
  for (int k=0;k<4;++k)
    tile[ty+8*k][tx] = src[(size_t)(by*32+ty+8*k)*DD + bx*32+tx];
  __syncthreads();
  #pragma unroll
  for (int k=0;k<4;++k)
    dst[(size_t)(bx*32+ty+8*k)*DD + by*32+tx] = tile[tx][ty+8*k];
}

// Per-batch prep: ego LN1 -> Ve -> v2; top-5; candidate x2; K5/V5;
// folded U5/eU5 (query side, pre-scaled) and W5 (output side); bias MLP.
// All global weight reads coalesced (pWq/eWq via pre-transposed copies).
__global__ __launch_bounds__(256) void prep_kernel(
  const float* __restrict__ tokens, const int* __restrict__ ego_idx,
  const float* __restrict__ dist,
  const float* __restrict__ ln1_g, const float* __restrict__ ln1_b,
  const float* __restrict__ ln2_g, const float* __restrict__ ln2_b,
  const float* __restrict__ cWv, const float* __restrict__ cWo,
  const float* __restrict__ pWqT, const float* __restrict__ eWqT,
  const float* __restrict__ pWk, const float* __restrict__ pWv,
  const float* __restrict__ pWo,
  const float* __restrict__ bW1, const float* __restrict__ bb1,
  const float* __restrict__ bW2, const float* __restrict__ bb2,
  float* __restrict__ v2g, int* __restrict__ candI,
  float* __restrict__ U5, float* __restrict__ eU5, float* __restrict__ W5,
  float* __restrict__ biasO)
{
  __shared__ float sA[DD], sB[DD], sV2[DD];
  __shared__ float sX2[NC][DD], sK5[NC][DD], sV5[NC][DD];
  __shared__ float red[8];
  __shared__ int sCI[NC];
  __shared__ float sCD[NC];
  __shared__ float sW1[2*BH], sB1[BH], sW2[BH*HH], sB2[HH];

  int b = blockIdx.x, t = threadIdx.x;
  int ego = ego_idx[b];

  if (t < 2*BH) sW1[t] = bW1[t];
  if (t < BH)   sB1[t] = bb1[t];
  for (int i=t;i<BH*HH;i+=256) sW2[i]=bW2[i];
  if (t < HH)   sB2[t] = bb2[t];

  // ---- LN1 on ego token ----
  float xe = tokens[((size_t)b*NN+ego)*DD + t];
  float a = xe, sq = xe*xe;
  breduce2(a, sq, red);
  float mu = a*(1.0f/DD), var = sq*(1.0f/DD)-mu*mu;
  float rs = rsqrtf(var+1e-5f);
  sA[t] = (xe-mu)*rs*ln1_g[t] + ln1_b[t];
  __syncthreads();
  // ---- Ve = x1e @ cWv ----
  {
    float acc=0.f;
    for (int d=0;d<DD;++d) acc += sA[d]*cWv[d*DD+t];
    sB[t]=acc;
  }
  __syncthreads();
  // ---- v2 = Ve @ cWo ----
  {
    float acc=0.f;
    for (int d=0;d<DD;++d) acc += sB[d]*cWo[d*DD+t];
    sV2[t]=acc;
    v2g[(size_t)b*DD+t]=acc;
  }
  // ---- top-5 smallest (dist, idx) packed u64 wave-min, wave 0 ----
  if (t < 64){
    unsigned long long k0 = (((unsigned long long)__float_as_uint(dist[b*NN+t]))<<32) | (unsigned)t;
    unsigned long long k1 = (((unsigned long long)__float_as_uint(dist[b*NN+t+64]))<<32) | (unsigned)(t+64);
    for (int r=0;r<NC;++r){
      unsigned long long m = k0<k1?k0:k1;
      #pragma unroll
      for (int s=32;s>=1;s>>=1){
        unsigned long long o = __shfl_xor(m, s);
        if (o<m) m=o;
      }
      int idx = (int)(m & 0xffffffffULL);
      if (t==0){
        sCI[r]=idx;
        sCD[r]=__uint_as_float((unsigned)(m>>32));
        candI[b*8+r]=idx;
      }
      if (idx==t)    k0=~0ULL;
      if (idx==t+64) k1=~0ULL;
    }
  }
  __syncthreads();
  // ---- candidate rows: x2 = LN2(tokens[cand] + v2) ----
  for (int c=0;c<NC;++c){
    float h1 = tokens[((size_t)b*NN+sCI[c])*DD + t] + sV2[t];
    float s=h1, s2=h1*h1;
    breduce2(s,s2,red);
    float m2 = s*(1.0f/DD), v = s2*(1.0f/DD)-m2*m2;
    float r2 = rsqrtf(v+1e-5f);
    sX2[c][t] = (h1-m2)*r2*ln2_g[t]+ln2_b[t];
  }
  __syncthreads();
  // ---- K5 = x2c @ pWk ; V5 = x2c @ pWv ----
  {
    float k0=0,k1=0,k2=0,k3=0,k4=0, v0=0,v1=0,v2=0,v3=0,v4=0;
    for (int d=0;d<DD;++d){
      float wk = pWk[d*DD+t], wv = pWv[d*DD+t];
      float xa=sX2[0][d], xb=sX2[1][d], xc=sX2[2][d], xd=sX2[3][d], xe2=sX2[4][d];
      k0+=xa*wk; k1+=xb*wk; k2+=xc*wk; k3+=xd*wk; k4+=xe2*wk;
      v0+=xa*wv; v1+=xb*wv; v2+=xc*wv; v3+=xd*wv; v4+=xe2*wv;
    }
    sK5[0][t]=k0; sK5[1][t]=k1; sK5[2][t]=k2; sK5[3][t]=k3; sK5[4][t]=k4;
    sV5[0][t]=v0; sV5[1][t]=v1; sV5[2][t]=v2; sV5[3][t]=v3; sV5[4][t]=v4;
  }
  __syncthreads();
  // ---- U5[c][h][i] = SCALE_INV * sum_dd pWqT[h*32+dd][i]*K5[c][h*32+dd] ----
  for (int h=0;h<HH;++h){
    float u0=0,u1=0,u2=0,u3=0,u4=0, e0=0,e1=0,e2=0,e3=0,e4=0;
    #pragma unroll
    for (int dd=0;dd<32;++dd){
      int d = h*32+dd;
      float wq = pWqT[(size_t)d*DD+t];   // coalesced (t across lanes)
      float we = eWqT[(size_t)d*DD+t];
      float a0=sK5[0][d], a1=sK5[1][d], a2=sK5[2][d], a3=sK5[3][d], a4=sK5[4][d];
      u0+=wq*a0; u1+=wq*a1; u2+=wq*a2; u3+=wq*a3; u4+=wq*a4;
      e0+=we*a0; e1+=we*a1; e2+=we*a2; e3+=we*a3; e4+=we*a4;
    }
    size_t base = (size_t)b*NC*HH*DD + (size_t)h*DD + t;
    U5 [base + 0*HH*DD]=u0*SCALE_INV; eU5[base + 0*HH*DD]=e0*SCALE_INV;
    U5 [base + 1*HH*DD]=u1*SCALE_INV; eU5[base + 1*HH*DD]=e1*SCALE_INV;
    U5 [base + 2*HH*DD]=u2*SCALE_INV; eU5[base + 2*HH*DD]=e2*SCALE_INV;
    U5 [base + 3*HH*DD]=u3*SCALE_INV; eU5[base + 3*HH*DD]=e3*SCALE_INV;
    U5 [base + 4*HH*DD]=u4*SCALE_INV; eU5[base + 4*HH*DD]=e4*SCALE_INV;
  }
  // ---- W5[c][h][j] = sum_dd V5[c][h*32+dd] * pWo[h*32+dd, j] ----
  for (int h=0;h<HH;++h){
    float w0=0,w1=0,w2=0,w3=0,w4=0;
    #pragma unroll
    for (int dd=0;dd<32;++dd){
      int d=h*32+dd;
      float wo = pWo[d*DD+t];
      w0+=sV5[0][d]*wo; w1+=sV5[1][d]*wo; w2+=sV5[2][d]*wo;
      w3+=sV5[3][d]*wo; w4+=sV5[4][d]*wo;
    }
    size_t base = (size_t)b*NC*HH*DD + (size_t)h*DD + t;
    W5[base + 0*HH*DD]=w0; W5[base + 1*HH*DD]=w1; W5[base + 2*HH*DD]=w2;
    W5[base + 3*HH*DD]=w3; W5[base + 4*HH*DD]=w4;
  }
  // ---- bias MLP table: bias[b][n][c][h] ----
  for (int p=t;p<NN*NC;p+=256){
    int n=p/NC, c=p%NC;
    float di = dist[b*NN+n], dj = sCD[c];
    float o0=0,o1=0,o2=0,o3=0,o4=0,o5=0,o6=0,o7=0;
    for (int j=0;j<BH;++j){
      float hd = fmaxf(di*sW1[j]+dj*sW1[BH+j]+sB1[j], 0.f);
      o0+=hd*sW2[j*HH+0]; o1+=hd*sW2[j*HH+1];
      o2+=hd*sW2[j*HH+2]; o3+=hd*sW2[j*HH+3];
      o4+=hd*sW2[j*HH+4]; o5+=hd*sW2[j*HH+5];
      o6+=hd*sW2[j*HH+6]; o7+=hd*sW2[j*HH+7];
    }
    float* bp = biasO + (((size_t)b*NN+n)*NC+c)*HH;
    bp[0]=o0+sB2[0]; bp[1]=o1+sB2[1]; bp[2]=o2+sB2[2]; bp[3]=o3+sB2[3];
    bp[4]=o4+sB2[4]; bp[5]=o5+sB2[5]; bp[6]=o6+sB2[6]; bp[7]=o7+sB2[7];
  }
}

// 8 named partials (one per h) -> lane holds full sum for h=lane>>3.
__device__ __forceinline__ float reduce40(
  float q0,float q1,float q2,float q3,float q4,float q5,float q6,float q7,int lane)
{
  const bool b5 = (lane&32)!=0, b4 = (lane&16)!=0, b3 = (lane&8)!=0;
  float r0 = (b5? q4:q0) + __shfl_xor(b5? q0:q4, 32);
  float r1 = (b5? q5:q1) + __shfl_xor(b5? q1:q5, 32);
  float r2 = (b5? q6:q2) + __shfl_xor(b5? q2:q6, 32);
  float r3 = (b5? q7:q3) + __shfl_xor(b5? q3:q7, 32);
  float t0 = (b4? r2:r0) + __shfl_xor(b4? r0:r2, 16);
  float t1 = (b4? r3:r1) + __shfl_xor(b4? r1:r3, 16);
  float s  = (b3? t1:t0) + __shfl_xor(b3? t0:t1, 8);
  s += __shfl_xor(s,4); s += __shfl_xor(s,2); s += __shfl_xor(s,1);
  return s;
}

#define DOT8(PTREXPR) \
  { const float* ub_ = (PTREXPR) + 4*lane; \
    float4 u; \
    u=*(const float4*)(ub_+0*DD); q0=x0*u.x+x1*u.y+x2*u.z+x3*u.w; \
    u=*(const float4*)(ub_+1*DD); q1=x0*u.x+x1*u.y+x2*u.z+x3*u.w; \
    u=*(const float4*)(ub_+2*DD); q2=x0*u.x+x1*u.y+x2*u.z+x3*u.w; \
    u=*(const float4*)(ub_+3*DD); q3=x0*u.x+x1*u.y+x2*u.z+x3*u.w; \
    u=*(const float4*)(ub_+4*DD); q4=x0*u.x+x1*u.y+x2*u.z+x3*u.w; \
    u=*(const float4*)(ub_+5*DD); q5=x0*u.x+x1*u.y+x2*u.z+x3*u.w; \
    u=*(const float4*)(ub_+6*DD); q6=x0*u.x+x1*u.y+x2*u.z+x3*u.w; \
    u=*(const float4*)(ub_+7*DD); q7=x0*u.x+x1*u.y+x2*u.z+x3*u.w; }

// One block per batch, 512 threads = 8 waves, wave per row (16 rows/wave).
// LDS: U5 + W5 = exactly 80 KB -> 2 blocks/CU. Zero per-lane arrays.
// (Round-3-proven structure; round-4's 4-row batching spilled to scratch.)
__global__ __launch_bounds__(512, 4) void main_kernel(
  const float* __restrict__ tokens, const int* __restrict__ ego_idx,
  const float* __restrict__ ln2_g, const float* __restrict__ ln2_b,
  const float* __restrict__ v2g, const int* __restrict__ candI,
  const float* __restrict__ U5g, const float* __restrict__ eU5g,
  const float* __restrict__ W5g, const float* __restrict__ biasO,
  float* __restrict__ out)
{
  __shared__ float sU[NC*HH*DD];
  __shared__ float sW[NC*HH*DD];
  int b = blockIdx.x, t = threadIdx.x;
  int lane = t & 63, wave = t >> 6;
  {
    const float4* srcU = (const float4*)(U5g + (size_t)b*NC*HH*DD);
    const float4* srcW = (const float4*)(W5g + (size_t)b*NC*HH*DD);
    float4* dU = (float4*)sU; float4* dW = (float4*)sW;
    #pragma unroll
    for (int i=0;i<5;++i){ dU[t+512*i]=srcU[t+512*i]; dW[t+512*i]=srcW[t+512*i]; }
  }
  int ego = ego_idx[b];
  const int* cip = candI + b*8;
  int ci0=cip[0],ci1=cip[1],ci2=cip[2],ci3=cip[3],ci4=cip[4];
  float4 v2r = *(const float4*)(v2g + (size_t)b*DD + 4*lane);
  float4 g4  = *(const float4*)(ln2_g + 4*lane);
  float4 b4  = *(const float4*)(ln2_b + 4*lane);
  int h_lane = lane>>3;
  __syncthreads();

  for (int n=wave; n<NN; n+=8){
    float4 tok = *(const float4*)(tokens + ((size_t)b*NN+n)*DD + 4*lane);
    // bias prefetch (issued early; lanes sharing h read same addr)
    const float* bp = biasO + ((size_t)b*NN+n)*NC*HH + h_lane;
    float bi0=bp[0], bi1=bp[8], bi2=bp[16], bi3=bp[24], bi4=bp[32];
    float h0=tok.x+v2r.x, h1=tok.y+v2r.y, h2=tok.z+v2r.z, h3=tok.w+v2r.w;
    // LN2 (wave butterfly over 64 lanes x 4 elems)
    float s1 = h0+h1+h2+h3;
    float s2 = h0*h0+h1*h1+h2*h2+h3*h3;
    #pragma unroll
    for (int m=32;m>=1;m>>=1){ s1+=__shfl_xor(s1,m); s2+=__shfl_xor(s2,m); }
    float mu = s1*(1.0f/DD);
    float var = s2*(1.0f/DD)-mu*mu;
    float rs = rsqrtf(var+1e-5f);
    float x0=(h0-mu)*rs*g4.x+b4.x;
    float x1=(h1-mu)*rs*g4.y+b4.y;
    float x2=(h2-mu)*rs*g4.z+b4.z;
    float x3=(h3-mu)*rs*g4.w+b4.w;
    // scores for all 5 candidates (U pre-scaled by 1/sqrt(hd))
    float q0,q1,q2,q3,q4,q5,q6,q7;
    float sc0,sc1,sc2,sc3,sc4;
    if (n==ego){
      const float* eb = eU5g + (size_t)b*NC*HH*DD;
      DOT8(eb + 0*HH*DD); sc0 = reduce40(q0,q1,q2,q3,q4,q5,q6,q7,lane);
      DOT8(eb + 1*HH*DD); sc1 = reduce40(q0,q1,q2,q3,q4,q5,q6,q7,lane);
      DOT8(eb + 2*HH*DD); sc2 = reduce40(q0,q1,q2,q3,q4,q5,q6,q7,lane);
      DOT8(eb + 3*HH*DD); sc3 = reduce40(q0,q1,q2,q3,q4,q5,q6,q7,lane);
      DOT8(eb + 4*HH*DD); sc4 = reduce40(q0,q1,q2,q3,q4,q5,q6,q7,lane);
    } else {
      DOT8(sU + 0*HH*DD); sc0 = reduce40(q0,q1,q2,q3,q4,q5,q6,q7,lane);
      DOT8(sU + 1*HH*DD); sc1 = reduce40(q0,q1,q2,q3,q4,q5,q6,q7,lane);
      DOT8(sU + 2*HH*DD); sc2 = reduce40(q0,q1,q2,q3,q4,q5,q6,q7,lane);
      DOT8(sU + 3*HH*DD); sc3 = reduce40(q0,q1,q2,q3,q4,q5,q6,q7,lane);
      DOT8(sU + 4*HH*DD); sc4 = reduce40(q0,q1,q2,q3,q4,q5,q6,q7,lane);
    }
    // mask: exclude self if among top-5, else exclude 5th candidate
    int pos = (ci0==n)?0:(ci1==n)?1:(ci2==n)?2:(ci3==n)?3:(ci4==n)?4:5;
    int bad = (pos==5)?4:pos;
    sc0 = (bad==0)? -1e30f : sc0+bi0;
    sc1 = (bad==1)? -1e30f : sc1+bi1;
    sc2 = (bad==2)? -1e30f : sc2+bi2;
    sc3 = (bad==3)? -1e30f : sc3+bi3;
    sc4 = (bad==4)? -1e30f : sc4+bi4;
    // lane-local softmax over 5 (each lane owns h=lane>>3, replicated x8)
    float mx = fmaxf(fmaxf(fmaxf(sc0,sc1),fmaxf(sc2,sc3)),sc4);
    float e0=__expf(sc0-mx), e1=__expf(sc1-mx), e2=__expf(sc2-mx);
    float e3=__expf(sc3-mx), e4=__expf(sc4-mx);
    float inv = 1.0f/(e0+e1+e2+e3+e4);
    float w0=e0*inv, w1=e1*inv, w2=e2*inv, w3=e3*inv, w4=e4*inv;
    // output: o[j] = sum_{c,h} w[c,h] * W5[c,h,j]
    float o0=0.f,o1=0.f,o2=0.f,o3=0.f;
    #pragma unroll
    for (int c=0;c<NC;++c){
      float wc = (c==0)?w0:(c==1)?w1:(c==2)?w2:(c==3)?w3:w4;
      #pragma unroll
      for (int h=0;h<HH;++h){
        float wv = __shfl(wc, h*8);   // lane h*8 holds h's weight
        const float4 wr = *(const float4*)(sW + (c*HH+h)*DD + 4*lane);
        o0+=wv*wr.x; o1+=wv*wr.y; o2+=wv*wr.z; o3+=wv*wr.w;
      }
    }
    float4 res = make_float4(h0+o0, h1+o1, h2+o2, h3+o3);
    *(float4*)(out + ((size_t)b*NN+n)*DD + 4*lane) = res;
  }
}

extern "C" void kernel_launch(void* const* d_in, const int* in_sizes, int n_in,
                              void* d_out, int out_size, void* d_ws, size_t ws_size,
                              hipStream_t stream) {
  (void)in_sizes; (void)n_in; (void)out_size; (void)ws_size;
  const float* tokens = (const float*)d_in[0];
  const int*   ego_idx= (const int*)  d_in[1];
  const float* dist   = (const float*)d_in[2];
  // d_in[3] = ego_speed (unused by reference)
  const float* ln1_g  = (const float*)d_in[4];
  const float* ln1_b  = (const float*)d_in[5];
  const float* ln2_g  = (const float*)d_in[6];
  const float* ln2_b  = (const float*)d_in[7];
  // d_in[8]=cWq, d_in[9]=cWk dead: softmax over singleton axis == 1
  const float* cWv    = (const float*)d_in[10];
  const float* cWo    = (const float*)d_in[11];
  const float* pWq    = (const float*)d_in[12];
  const float* eWq    = (const float*)d_in[13];
  const float* pWk    = (const float*)d_in[14];
  const float* pWv    = (const float*)d_in[15];
  const float* pWo    = (const float*)d_in[16];
  const float* bW1    = (const float*)d_in[17];
  const float* bb1    = (const float*)d_in[18];
  const float* bW2    = (const float*)d_in[19];
  const float* bb2    = (const float*)d_in[20];
  float* outp = (float*)d_out;

  char* w = (char*)d_ws;
  float* v2g   = (float*)w; w += (size_t)BB*DD*4;
  int*   candI = (int*)w;   w += (size_t)BB*8*4;
  float* U5    = (float*)w; w += (size_t)BB*NC*HH*DD*4;
  float* eU5   = (float*)w; w += (size_t)BB*NC*HH*DD*4;
  float* W5    = (float*)w; w += (size_t)BB*NC*HH*DD*4;
  float* biasO = (float*)w; w += (size_t)BB*NN*NC*HH*4;
  float* pWqT  = (float*)w; w += (size_t)DD*DD*4;
  float* eWqT  = (float*)w; w += (size_t)DD*DD*4;

  transpose_kernel<<<dim3(8,8,2), dim3(256), 0, stream>>>(pWq, eWq, pWqT, eWqT);

  prep_kernel<<<dim3(BB), dim3(256), 0, stream>>>(
      tokens, ego_idx, dist, ln1_g, ln1_b, ln2_g, ln2_b,
      cWv, cWo, pWqT, eWqT, pWk, pWv, pWo, bW1, bb1, bW2, bb2,
      v2g, candI, U5, eU5, W5, biasO);

  main_kernel<<<dim3(BB), dim3(512), 0, stream>>>(
      tokens, ego_idx, ln2_g, ln2_b, v2g, candI, U5, eU5, W5, biasO, outp);
}